// Round 4
// baseline (101.496 us; speedup 1.0000x reference)
//
#include <hip/hip_runtime.h>
#include <math.h>

// Problem constants
#define NW 16384      // B*S words
#define Tt 16         // chars per word
#define Vv 262        // vocab
#define Hh 32         // GRU hidden per direction
#define G3 96         // 3*H

// ws layout (floats) — identical to the verified round-2 layout:
//   [0, GFLOATS)      G table [2][262][96] = emb@Wih^T + bih (+bhh for r,z gates)
//   [BHI_FOFF, +3072) Whh fragments, bf16 hi parts [2][6][64 lanes][8] ushort
//   [BLO_FOFF, +3072) Whh fragments, bf16 lo parts
// Fragment value at (dir, chunk c, lane l=(m,q), elem i) = Whh[16c+m][8q+i],
// which serves as the MFMA *A* operand (rows = gates) in the swapped form.
#define GDIRF    (Vv*G3)            // 25152
#define GFLOATS  (2*GDIRF)          // 50304
#define BHI_FOFF GFLOATS
#define BLO_FOFF (GFLOATS + 3072)

typedef float        f32x4  __attribute__((ext_vector_type(4)));
typedef short        bf16x8 __attribute__((ext_vector_type(8)));
typedef unsigned int u32;
typedef u32          u32x4  __attribute__((ext_vector_type(4)));
typedef int          i32x4  __attribute__((ext_vector_type(4)));

__device__ __forceinline__ unsigned short bf16_rtne(float f) {
    u32 u = __builtin_bit_cast(u32, f);
    u += 0x7fffu + ((u >> 16) & 1u);
    return (unsigned short)(u >> 16);
}
__device__ __forceinline__ u32 pk_bf16(float a, float b) {
    u32 r;
    asm("v_cvt_pk_bf16_f32 %0, %1, %2" : "=v"(r) : "v"(a), "v"(b));
    return r;
}
__device__ __forceinline__ float fsigm(float x) {
    return __builtin_amdgcn_rcpf(1.0f + __expf(-x));
}
__device__ __forceinline__ float ftanh(float x) {
    return 1.0f - 2.0f * __builtin_amdgcn_rcpf(1.0f + __expf(2.0f * x));
}

// ---------------------------------------------------------------------------
// Precompute — verbatim the round-2 verified kernel.
// ---------------------------------------------------------------------------
__global__ __launch_bounds__(256) void precomp(
    const float* __restrict__ emb,
    const float* __restrict__ Wih_f, const float* __restrict__ Whh_f,
    const float* __restrict__ bih_f, const float* __restrict__ bhh_f,
    const float* __restrict__ Wih_b, const float* __restrict__ Whh_b,
    const float* __restrict__ bih_b, const float* __restrict__ bhh_b,
    float* __restrict__ ws)
{
    int b = blockIdx.x;
    if (b < 197) {
        int idx = b * 256 + threadIdx.x;
        if (idx >= GFLOATS) return;
        int dir = idx / GDIRF;
        int rem = idx - dir * GDIRF;
        int v = rem / G3;
        int g = rem - v * G3;
        const float* Wih = dir ? Wih_b : Wih_f;
        float acc = (dir ? bih_b : bih_f)[g];
        if (g < 64) acc += (dir ? bhh_b : bhh_f)[g];   // fold bhh for r,z only
        const f32x4* er = (const f32x4*)(emb + v * 64);
        const f32x4* wr = (const f32x4*)(Wih + g * 64);
        float s = 0.0f;
        #pragma unroll
        for (int e = 0; e < 16; ++e) {
            f32x4 a = er[e], w = wr[e];
            s = fmaf(a[0], w[0], s);
            s = fmaf(a[1], w[1], s);
            s = fmaf(a[2], w[2], s);
            s = fmaf(a[3], w[3], s);
        }
        ws[idx] = acc + s;
    } else {
        int t = (b - 197) * 256 + threadIdx.x;
        if (t >= 768) return;
        int dir = t / 384;
        int r2  = t - dir * 384;
        int c   = r2 >> 6;          // gate chunk 0..5
        int l   = r2 & 63;          // lane
        int m   = l & 15, q = l >> 4;
        const float* Whh = dir ? Whh_b : Whh_f;
        const float* row = Whh + (16 * c + m) * Hh + 8 * q;
        u32 hiw[4], low[4];
        #pragma unroll
        for (int p = 0; p < 4; ++p) {
            float f0 = row[2 * p], f1 = row[2 * p + 1];
            unsigned short h0 = bf16_rtne(f0), h1 = bf16_rtne(f1);
            float rr0 = f0 - __builtin_bit_cast(float, (u32)h0 << 16);
            float rr1 = f1 - __builtin_bit_cast(float, (u32)h1 << 16);
            unsigned short l0 = bf16_rtne(rr0), l1 = bf16_rtne(rr1);
            hiw[p] = (u32)h0 | ((u32)h1 << 16);
            low[p] = (u32)l0 | ((u32)l1 << 16);
        }
        u32x4* dh = (u32x4*)(ws + BHI_FOFF) + (dir * 6 + c) * 64 + l;
        u32x4* dl = (u32x4*)(ws + BLO_FOFF) + (dir * 6 + c) * 64 + l;
        u32x4 vh = {hiw[0], hiw[1], hiw[2], hiw[3]};
        u32x4 vl = {low[0], low[1], low[2], low[3]};
        *dh = vh;
        *dl = vl;
    }
}

// ---------------------------------------------------------------------------
// Main: one wave = (16 words, 1 dir). Swapped MFMA: D[gate][word] = Whh·h^T.
// Lane (m = lane&15, q = lane>>4) owns word m; holds h/gi/gates for units
// {4q+r, 16+4q+r}. h frag for next step built by register butterfly:
//   phase1: v_permlane32_swap (lane-bit5 <-> reg-bit1)
//   phase2: v_permlane16_swap (lane-bit4 <-> reg-bit1)
// No LDS in the recurrence loop; no barriers anywhere.
// ---------------------------------------------------------------------------
__global__ __launch_bounds__(256, 2) void gru_main(
    const int*   __restrict__ x,
    const float* __restrict__ ws,
    const float* __restrict__ bhh_f,
    const float* __restrict__ bhh_b,
    float*       __restrict__ out)
{
    __shared__ int chs[4][16 * 17];      // per-wave char staging (stride 17)

    const int tid  = threadIdx.x;
    const int lane = tid & 63;
    const int widx = tid >> 6;
    const int wave = blockIdx.x * 4 + widx;
    const int dir  = wave & 1;
    const int wg   = wave >> 1;
    const int m = lane & 15, q = lane >> 4;

    // stage this wave's 16 words x 16 chars (same-wave LDS, no barrier)
    {
        i32x4 cv = *(const i32x4*)(x + wg * 256 + lane * 4);
        #pragma unroll
        for (int j2 = 0; j2 < 4; ++j2) {
            int p = lane * 4 + j2;
            chs[widx][(p >> 4) * 17 + (p & 15)] = cv[j2];
        }
    }

    // Whh fragments (hi/lo), used as MFMA A operand
    bf16x8 whi[6], wlo[6];
    {
        const u32x4* ph = (const u32x4*)(ws + BHI_FOFF) + dir * 384 + lane;
        const u32x4* pl = (const u32x4*)(ws + BLO_FOFF) + dir * 384 + lane;
        #pragma unroll
        for (int c = 0; c < 6; ++c) {
            whi[c] = __builtin_bit_cast(bf16x8, ph[c * 64]);
            wlo[c] = __builtin_bit_cast(bf16x8, pl[c * 64]);
        }
    }
    const float* bhh = dir ? bhh_b : bhh_f;
    const f32x4 bnA = *(const f32x4*)(bhh + 64 + 4 * q);   // bhh_n gates 64+4q+r
    const f32x4 bnB = *(const f32x4*)(bhh + 80 + 4 * q);   // gates 80+4q+r
    const float* Gt = ws + dir * GDIRF;

    f32x4 hA = {0.f, 0.f, 0.f, 0.f};     // h[word m][4q+r]
    f32x4 hB = {0.f, 0.f, 0.f, 0.f};     // h[word m][16+4q+r]
    f32x4 mxA = {-3e38f, -3e38f, -3e38f, -3e38f};
    f32x4 mxB = {-3e38f, -3e38f, -3e38f, -3e38f};

    int* ch = chs[widx];
    const int t0 = dir ? 15 : 0;
    const int sg = dir ? -1 : 1;

    f32x4 GA[6], GB[6];                  // gi ping-pong: chunk c = gates 16c+4q+r
    int cn;                              // char for the next gload

    auto gload = [&](f32x4 (&G)[6], int v) {
        const float* gp = Gt + v * G3 + 4 * q;
        #pragma unroll
        for (int c = 0; c < 6; ++c) G[c] = *(const f32x4*)(gp + 16 * c);
    };

    auto gates = [&](const f32x4 (&acc)[6], const f32x4& gnA, const f32x4& gnB) {
        #pragma unroll
        for (int r = 0; r < 4; ++r) {
            float rr = fsigm(acc[0][r]);
            float zz = fsigm(acc[2][r]);
            float nn = ftanh(fmaf(rr, acc[4][r], gnA[r]));
            float hx = nn + zz * (hA[r] - nn);
            mxA[r] = fmaxf(mxA[r], hx);
            hA[r] = hx;

            float rb = fsigm(acc[1][r]);
            float zb = fsigm(acc[3][r]);
            float nb = ftanh(fmaf(rb, acc[5][r], gnB[r]));
            float hy = nb + zb * (hB[r] - nb);
            mxB[r] = fmaxf(mxB[r], hy);
            hB[r] = hy;
        }
    };

    // D-layout -> B-layout butterfly on 4 packed-bf16 u32s
    auto bfly = [&](u32& k0, u32& k1, u32& k2, u32& k3) {
        asm volatile("v_permlane32_swap_b32 %0, %1" : "+v"(k0), "+v"(k2));
        asm volatile("v_permlane32_swap_b32 %0, %1" : "+v"(k1), "+v"(k3));
        asm volatile("v_permlane16_swap_b32 %0, %1" : "+v"(k0), "+v"(k2));
        asm volatile("v_permlane16_swap_b32 %0, %1" : "+v"(k1), "+v"(k3));
    };

    auto mkfrag = [&](bf16x8& Bhi, bf16x8& Blo) {
        u32 k0 = pk_bf16(hA[0], hA[1]), k1 = pk_bf16(hA[2], hA[3]);
        u32 k2 = pk_bf16(hB[0], hB[1]), k3 = pk_bf16(hB[2], hB[3]);
        float e0 = __builtin_bit_cast(float, k0 << 16);
        float o0 = __builtin_bit_cast(float, k0 & 0xffff0000u);
        float e1 = __builtin_bit_cast(float, k1 << 16);
        float o1 = __builtin_bit_cast(float, k1 & 0xffff0000u);
        float e2 = __builtin_bit_cast(float, k2 << 16);
        float o2 = __builtin_bit_cast(float, k2 & 0xffff0000u);
        float e3 = __builtin_bit_cast(float, k3 << 16);
        float o3 = __builtin_bit_cast(float, k3 & 0xffff0000u);
        u32 l0 = pk_bf16(hA[0] - e0, hA[1] - o0);
        u32 l1 = pk_bf16(hA[2] - e1, hA[3] - o1);
        u32 l2 = pk_bf16(hB[0] - e2, hB[1] - o2);
        u32 l3 = pk_bf16(hB[2] - e3, hB[3] - o3);
        bfly(k0, k1, k2, k3);
        bfly(l0, l1, l2, l3);
        u32x4 hq = {k0, k1, k2, k3};
        u32x4 lq = {l0, l1, l2, l3};
        Bhi = __builtin_bit_cast(bf16x8, hq);
        Blo = __builtin_bit_cast(bf16x8, lq);
    };

    auto step = [&](const f32x4 (&Gc)[6], f32x4 (&Gn)[6], int t) {
        if (t < 15) gload(Gn, cn);                       // prefetch gi(t+1)
        if (t < 14) cn = ch[m * 17 + t0 + (t + 2) * sg]; // char(t+2)
        bf16x8 Bhi, Blo;
        mkfrag(Bhi, Blo);
        f32x4 acc[6] = {Gc[0], Gc[1], Gc[2], Gc[3], bnA, bnB};
        #pragma unroll
        for (int c = 0; c < 6; ++c) {
            acc[c] = __builtin_amdgcn_mfma_f32_16x16x32_bf16(wlo[c], Bhi, acc[c], 0, 0, 0);
            acc[c] = __builtin_amdgcn_mfma_f32_16x16x32_bf16(whi[c], Blo, acc[c], 0, 0, 0);
            acc[c] = __builtin_amdgcn_mfma_f32_16x16x32_bf16(whi[c], Bhi, acc[c], 0, 0, 0);
        }
        gates(acc, Gc[4], Gc[5]);
    };

    // prologue: G(0) -> GA, G(1) -> GB, char(2) -> cn
    int c0 = ch[m * 17 + t0];
    gload(GA, c0);
    int c1 = ch[m * 17 + t0 + sg];
    gload(GB, c1);
    cn = ch[m * 17 + t0 + 2 * sg];

    // step 0: h=0 -> gh=0, no MFMA
    {
        f32x4 acc[6] = {GA[0], GA[1], GA[2], GA[3], bnA, bnB};
        gates(acc, GA[4], GA[5]);
    }

    // steps 1..15, GA/GB ping-pong
    step(GB, GA, 1);
    #pragma unroll 1
    for (int it = 0; it < 7; ++it) {
        step(GA, GB, 2 + 2 * it);
        step(GB, GA, 3 + 2 * it);
    }

    // store: out[word][dir*32 + unit]; 2x coalesced f32x4 per lane
    const int ob = (wg * 16 + m) * 64 + dir * 32 + 4 * q;
    *(f32x4*)(out + ob)      = mxA;
    *(f32x4*)(out + ob + 16) = mxB;
}

extern "C" void kernel_launch(void* const* d_in, const int* in_sizes, int n_in,
                              void* d_out, int out_size, void* d_ws, size_t ws_size,
                              hipStream_t stream) {
    const int*   x     = (const int*)  d_in[0];
    const float* emb   = (const float*)d_in[1];
    const float* Wih_f = (const float*)d_in[2];
    const float* Whh_f = (const float*)d_in[3];
    const float* bih_f = (const float*)d_in[4];
    const float* bhh_f = (const float*)d_in[5];
    const float* Wih_b = (const float*)d_in[6];
    const float* Whh_b = (const float*)d_in[7];
    const float* bih_b = (const float*)d_in[8];
    const float* bhh_b = (const float*)d_in[9];
    float* out = (float*)d_out;
    float* ws  = (float*)d_ws;

    precomp<<<200, 256, 0, stream>>>(emb, Wih_f, Whh_f, bih_f, bhh_f,
                                     Wih_b, Whh_b, bih_b, bhh_b, ws);
    gru_main<<<512, 256, 0, stream>>>(x, ws, bhh_f, bhh_b, out);
}